// Round 7
// baseline (218.807 us; speedup 1.0000x reference)
//
#include <hip/hip_runtime.h>
#include <hip/hip_bf16.h>
#include <cstddef>

#define DIMC   768
#define HEADS  12
#define BATCH  4
#define SEQ    2048
#define MROWS  (BATCH * SEQ)      // 8192
#define NCAT   1920               // 768 (Wa) + 384 (Wb) + 768 (Wv)

typedef unsigned short u16;
typedef __attribute__((ext_vector_type(8))) short short8;   // 8 bf16 = 4 VGPRs
typedef __attribute__((ext_vector_type(4))) float floatx4;  // MFMA C/D

__device__ inline u16 f2bf(float f) {
    union { float f; unsigned u; } v; v.f = f;
    unsigned u = v.u + 0x7FFF + ((v.u >> 16) & 1);   // RNE
    return (u16)(u >> 16);
}
__device__ inline float bf2f(u16 h) {
    union { unsigned u; float f; } v; v.u = ((unsigned)h) << 16;
    return v.f;
}

// async 16B/lane global->LDS; lane i lands at lptr + i*16 (wave-uniform base)
__device__ inline void async_load16(const void* g, void* l) {
    __builtin_amdgcn_global_load_lds(
        (const __attribute__((address_space(1))) void*)g,
        (__attribute__((address_space(3))) void*)l, 16, 0, 0);
}

// ---------------------------------------------------------------------------
// Fused prep: blocks [0,3072): x fp32 -> xb bf16 (8 elem/thread).
// Blocks [3072,3432): Wtcat 64x64 tile-transpose; [3432,3576): Wpt.
// ---------------------------------------------------------------------------
__global__ __launch_bounds__(256)
void prep_kernel(const float* __restrict__ x,
                 const float* __restrict__ Wa, const float* __restrict__ Wb,
                 const float* __restrict__ Wv, const float* __restrict__ Wp,
                 u16* __restrict__ xb, u16* __restrict__ Wtcat, u16* __restrict__ Wpt)
{
    const int tid = threadIdx.x;
    if (blockIdx.x < 3072) {
        int i = blockIdx.x * 256 + tid;
        const float4 f0 = ((const float4*)x)[(size_t)i * 2];
        const float4 f1 = ((const float4*)x)[(size_t)i * 2 + 1];
        u16 tmp[8] = { f2bf(f0.x), f2bf(f0.y), f2bf(f0.z), f2bf(f0.w),
                       f2bf(f1.x), f2bf(f1.y), f2bf(f1.z), f2bf(f1.w) };
        *(uint4*)&xb[(size_t)i * 8] = *(uint4*)tmp;
        return;
    }
    __shared__ u16 tile[64 * 72];
    int bid = blockIdx.x - 3072;
    const float* src; u16* dst; int n0, k0, ld, col0;
    if (bid < 360) {
        int nt = bid / 12, kt = bid % 12;
        n0 = nt * 64; k0 = kt * 64; dst = Wtcat;
        if (n0 < 768)       { src = Wa; ld = 768; col0 = n0; }
        else if (n0 < 1152) { src = Wb; ld = 384; col0 = n0 - 768; }
        else                { src = Wv; ld = 768; col0 = n0 - 1152; }
    } else {
        int b2 = bid - 360;
        int nt = b2 / 12, kt = b2 % 12;
        n0 = nt * 64; k0 = kt * 64; dst = Wpt; src = Wp; ld = 768; col0 = n0;
    }
#pragma unroll
    for (int p = 0; p < 16; ++p) {
        int i = p * 256 + tid;
        int k = i >> 6, n = i & 63;
        tile[n * 72 + k] = f2bf(src[(size_t)(k0 + k) * ld + col0 + n]);
    }
    __syncthreads();
    int n = tid >> 2, kc = (tid & 3) * 16;
    uint4 o0 = *(uint4*)&tile[n * 72 + kc];
    uint4 o1 = *(uint4*)&tile[n * 72 + kc + 8];
    *(uint4*)&dst[(size_t)(n0 + n) * DIMC + k0 + kc] = o0;
    *(uint4*)&dst[(size_t)(n0 + n) * DIMC + k0 + kc + 8] = o1;
}

// ---------------------------------------------------------------------------
// bf16 MFMA GEMM, 128x128 tile, BK=32.
//  - A: async global_load_lds staging, XOR-swizzled so ds_read_b128 fragment
//    reads are bank-conflict-free. Double-buffered, raw s_barrier pipeline.
//  - B (weights, L2-resident): direct global->VGPR fragment loads,
//    register double-buffered (no LDS at all for B).
//  - steady-state s_waitcnt vmcnt(6): retires older Astage(2)+Bload(4),
//    keeps the newer 6 in flight across the barrier.
// ---------------------------------------------------------------------------
template<bool WRITE_BF16>
__global__ __launch_bounds__(256)
void gemm_bf16_kernel(const u16* __restrict__ A, const u16* __restrict__ Bt,
                      const float* __restrict__ bias, void* __restrict__ Cout,
                      int K, int ldC)
{
    __shared__ u16 As[2][128 * 32];

    const int tid  = threadIdx.x;
    const int lane = tid & 63, wave = tid >> 6;
    const int quad = lane >> 4, l16 = lane & 15;
    const int wm = (wave & 1) * 64, wn = (wave >> 1) * 64;
    const int m0 = blockIdx.x * 128, n0 = blockIdx.y * 128;

    // A staging: lane -> row (lane>>2), chunk swizzled by row-pair
    const int lrow   = lane >> 2;
    const int lchunk = (lane & 3) ^ ((lane >> 3) & 3);
    const u16* gA = A + (size_t)(m0 + wave * 32 + lrow) * K + lchunk * 8;

    // B fragment base: lane reads Bt[n0+wn+nt*16+l16][k + quad*8]
    const u16* gB = Bt + (size_t)(n0 + wn + l16) * K + quad * 8;
    const size_t bnt = (size_t)16 * K;   // nt stride

    const int NT = K / 32;   // 24
    // swizzled A-read chunk per fragment row
    const int sw = quad ^ ((l16 >> 1) & 3);

#define ASTAGE(buf, kt_) do {                                                 \
        const int _k0 = (kt_) * 32;                                           \
        async_load16(gA + _k0,          &As[buf][wave * 1024]);               \
        async_load16(gA + _k0 + 16 * K, &As[buf][wave * 1024 + 512]);         \
    } while (0)

#define BLOAD(reg, kt_) do {                                                  \
        const int _k0 = (kt_) * 32;                                           \
        _Pragma("unroll")                                                     \
        for (int nt = 0; nt < 4; ++nt)                                        \
            reg[nt] = *(const short8*)(gB + (size_t)nt * bnt + _k0);          \
    } while (0)

#define COMPUTE(buf, breg) do {                                               \
        short8 af[4];                                                         \
        _Pragma("unroll")                                                     \
        for (int t = 0; t < 4; ++t)                                           \
            af[t] = *(short8*)&As[buf][(wm + t * 16 + l16) * 32 + sw * 8];    \
        _Pragma("unroll")                                                     \
        for (int mt = 0; mt < 4; ++mt)                                        \
            _Pragma("unroll")                                                 \
            for (int nt = 0; nt < 4; ++nt)                                    \
                acc[mt][nt] = __builtin_amdgcn_mfma_f32_16x16x32_bf16(        \
                    af[mt], breg[nt], acc[mt][nt], 0, 0, 0);                  \
    } while (0)

    floatx4 acc[4][4] = {};
    short8 b0[4], b1[4];

    // prologue (issue order matters for vmcnt FIFO): A0(2), B0(4), A1(2)
    ASTAGE(0, 0);
    BLOAD(b0, 0);
    ASTAGE(1, 1);

    for (int kt = 0; kt < NT; kt += 2) {
        BLOAD(b1, kt + 1);                    // outstanding: A0 B0 A1 B1 = 12
        __asm__ volatile("s_waitcnt vmcnt(6)" ::: "memory");   // retire A0,B0
        __asm__ volatile("s_barrier" ::: "memory");
        COMPUTE(0, b0);
        __asm__ volatile("s_barrier" ::: "memory");
        ASTAGE(0, (kt + 2) % NT);
        BLOAD(b0, (kt + 2) % NT);             // outstanding: A1 B1 A0' B0' = 12
        __asm__ volatile("s_waitcnt vmcnt(6)" ::: "memory");   // retire A1,B1
        __asm__ volatile("s_barrier" ::: "memory");
        COMPUTE(1, b1);
        __asm__ volatile("s_barrier" ::: "memory");
        ASTAGE(1, (kt + 3) % NT);
    }
#undef ASTAGE
#undef BLOAD
#undef COMPUTE

#pragma unroll
    for (int mt = 0; mt < 4; ++mt) {
#pragma unroll
        for (int nt = 0; nt < 4; ++nt) {
            const int gc = n0 + wn + nt * 16 + l16;
            const float bv = bias ? bias[gc] : 0.f;
#pragma unroll
            for (int r = 0; r < 4; ++r) {
                const int gr = m0 + wm + mt * 16 + quad * 4 + r;
                const float v = acc[mt][nt][r] + bv;
                if (WRITE_BF16) ((u16*)Cout)[(size_t)gr * ldC + gc] = f2bf(v);
                else            ((float*)Cout)[(size_t)gr * ldC + gc] = v;
            }
        }
    }
}

// ---------------------------------------------------------------------------
// Pool V (vectorized): Vs[bh][t][d] = sum_{j<32} Ycat[b, 32t+j, 1152+h*64+d]
// ---------------------------------------------------------------------------
__global__ __launch_bounds__(256)
void pool_v_kernel(const u16* __restrict__ Ycat, float* __restrict__ Vs)
{
    int idx = blockIdx.x * 256 + threadIdx.x;     // < 24576
    int dc = idx & 7;
    int t  = (idx >> 3) & 63;
    int bh = idx >> 9;
    int h = bh % HEADS, b = bh / HEADS;
    const u16* src = Ycat + (size_t)(b * SEQ + t * 32) * NCAT + 1152 + h * 64 + dc * 8;
    float s[8] = {};
#pragma unroll
    for (int j = 0; j < 32; ++j) {
        uint4 v = *(const uint4*)&src[(size_t)j * NCAT];
        const u16* e = (const u16*)&v;
#pragma unroll
        for (int q = 0; q < 8; ++q) s[q] += bf2f(e[q]);
    }
    float4* dst = (float4*)&Vs[(size_t)bh * 4096 + t * 64 + dc * 8];
    dst[0] = make_float4(s[0], s[1], s[2], s[3]);
    dst[1] = make_float4(s[4], s[5], s[6], s[7]);
}

// ---------------------------------------------------------------------------
// Attention via MFMA. Block = (bh, 64-row strip); wave owns 16 rows.
// ---------------------------------------------------------------------------
__global__ __launch_bounds__(256)
void attn_kernel(const u16* __restrict__ Ycat, const float* __restrict__ Vs,
                 u16* __restrict__ Hb)
{
    __shared__ u16 vsT[64 * 64];        // [d][k]
    __shared__ u16 wlds[4][16 * 64];    // per-wave P [r][k]
    const int bh = blockIdx.x;
    const int h = bh % HEADS, b = bh / HEADS;
    const int tid = threadIdx.x;

    for (int i = tid; i < 4096; i += 256) {
        int t = i >> 6, d = i & 63;
        vsT[d * 64 + t] = f2bf(Vs[(size_t)bh * 4096 + i]);
    }
    __syncthreads();

    const int lane = tid & 63, wave = tid >> 6;
    const int quad = lane >> 4, l16 = lane & 15;

    short8 bfrag[4][2];
#pragma unroll
    for (int nt = 0; nt < 4; ++nt)
#pragma unroll
        for (int kk = 0; kk < 2; ++kk)
            bfrag[nt][kk] = *(short8*)&vsT[(nt * 16 + l16) * 64 + kk * 32 + quad * 8];

    const int i0 = blockIdx.y * 64 + wave * 16;

    for (int r = 0; r < 16; ++r) {
        const size_t row = (size_t)(b * SEQ + i0 + r);
        float aval = bf2f(Ycat[row * NCAT + h * 64 + lane]);
        float bval = bf2f(Ycat[row * NCAT + 768 + h * 32 + (lane >> 1)]);
        float s = aval * bval;
        float m = s;
#pragma unroll
        for (int off = 32; off; off >>= 1) m = fmaxf(m, __shfl_xor(m, off, 64));
        float e = __expf(s - m);
        float sum = e;
#pragma unroll
        for (int off = 32; off; off >>= 1) sum += __shfl_xor(sum, off, 64);
        wlds[wave][r * 64 + lane] = f2bf(e / (32.0f * sum));
    }

    short8 af0 = *(short8*)&wlds[wave][l16 * 64 + quad * 8];
    short8 af1 = *(short8*)&wlds[wave][l16 * 64 + 32 + quad * 8];

    floatx4 acc[4] = {};
#pragma unroll
    for (int nt = 0; nt < 4; ++nt) {
        acc[nt] = __builtin_amdgcn_mfma_f32_16x16x32_bf16(af0, bfrag[nt][0], acc[nt], 0, 0, 0);
        acc[nt] = __builtin_amdgcn_mfma_f32_16x16x32_bf16(af1, bfrag[nt][1], acc[nt], 0, 0, 0);
    }

#pragma unroll
    for (int nt = 0; nt < 4; ++nt)
#pragma unroll
        for (int rr = 0; rr < 4; ++rr) {
            const size_t row = (size_t)(b * SEQ + i0 + quad * 4 + rr);
            Hb[row * DIMC + h * 64 + nt * 16 + l16] = f2bf(acc[nt][rr]);
        }
}

// ---------------------------------------------------------------------------
extern "C" void kernel_launch(void* const* d_in, const int* in_sizes, int n_in,
                              void* d_out, int out_size, void* d_ws, size_t ws_size,
                              hipStream_t stream)
{
    const float* x  = (const float*)d_in[0];
    const float* Wa = (const float*)d_in[1];
    const float* Wb = (const float*)d_in[2];
    const float* Wv = (const float*)d_in[3];
    const float* Wp = (const float*)d_in[4];
    const float* bp = (const float*)d_in[5];
    float* out = (float*)d_out;

    char* ws = (char*)d_ws;
    u16*   xb    = (u16*)ws;   ws += (size_t)MROWS * DIMC * 2;
    u16*   Wtcat = (u16*)ws;   ws += (size_t)NCAT * DIMC * 2;
    u16*   Wpt   = (u16*)ws;   ws += (size_t)DIMC * DIMC * 2;
    u16*   Ycat  = (u16*)ws;   ws += (size_t)MROWS * NCAT * 2;
    float* Vs    = (float*)ws; ws += (size_t)48 * 4096 * 4;
    u16*   Hb    = (u16*)ws;

    dim3 blk(256);

    prep_kernel<<<dim3(3576), blk, 0, stream>>>(x, Wa, Wb, Wv, Wp, xb, Wtcat, Wpt);

    gemm_bf16_kernel<true><<<dim3(MROWS / 128, NCAT / 128), blk, 0, stream>>>(
        xb, Wtcat, nullptr, Ycat, DIMC, NCAT);

    pool_v_kernel<<<dim3(96), blk, 0, stream>>>(Ycat, Vs);

    attn_kernel<<<dim3(BATCH * HEADS, SEQ / 64), blk, 0, stream>>>(Ycat, Vs, Hb);

    gemm_bf16_kernel<false><<<dim3(MROWS / 128, DIMC / 128), blk, 0, stream>>>(
        Hb, Wpt, bp, out, DIMC, DIMC);
}

// Round 10
// 180.750 us; speedup vs baseline: 1.2105x; 1.2105x over previous
//
#include <hip/hip_runtime.h>
#include <hip/hip_bf16.h>
#include <cstddef>

#define DIMC   768
#define HEADS  12
#define BATCH  4
#define SEQ    2048
#define MROWS  (BATCH * SEQ)      // 8192
#define NCAT   1920               // Wtcat rows: 768 (Wa) + 384 (Wb) + 768 (Wv)
#define NAB    1152               // gemm1 output width ([Wa|Wb] only)

typedef unsigned short u16;
typedef __attribute__((ext_vector_type(8))) short short8;   // 8 bf16 = 4 VGPRs
typedef __attribute__((ext_vector_type(4))) float floatx4;  // MFMA C/D

__device__ inline u16 f2bf(float f) {
    union { float f; unsigned u; } v; v.f = f;
    unsigned u = v.u + 0x7FFF + ((v.u >> 16) & 1);   // RNE
    return (u16)(u >> 16);
}
__device__ inline float bf2f(u16 h) {
    union { unsigned u; float f; } v; v.u = ((unsigned)h) << 16;
    return v.f;
}

// async 16B/lane global->LDS; lane i lands at lptr + i*16 (wave-uniform base)
__device__ inline void async_load16(const void* g, void* l) {
    __builtin_amdgcn_global_load_lds(
        (const __attribute__((address_space(1))) void*)g,
        (__attribute__((address_space(3))) void*)l, 16, 0, 0);
}

// ---------------------------------------------------------------------------
// Fused prep (R5-verbatim + xs section):
//  [0,3072)      x fp32 -> xb bf16 (8 elem/thread)
//  [3072,3432)   Wtcat 64x64 tile-transpose from [Wa|Wb|Wv]   (R5-exact)
//  [3432,3576)   Wpt from Wp                                  (R5-exact)
//  [3576,3832)   xs-pool: xs[p][c] = sum_{j<32} x[(p*32+j)*768 + c] (bf16)
// ---------------------------------------------------------------------------
__global__ __launch_bounds__(256)
void prep_kernel(const float* __restrict__ x,
                 const float* __restrict__ Wa, const float* __restrict__ Wb,
                 const float* __restrict__ Wv, const float* __restrict__ Wp,
                 u16* __restrict__ xb, u16* __restrict__ Wtcat,
                 u16* __restrict__ Wpt, u16* __restrict__ xs)
{
    const int tid = threadIdx.x;
    const int bidg = blockIdx.x;
    if (bidg < 3072) {
        int i = bidg * 256 + tid;
        const float4 f0 = ((const float4*)x)[(size_t)i * 2];
        const float4 f1 = ((const float4*)x)[(size_t)i * 2 + 1];
        u16 tmp[8] = { f2bf(f0.x), f2bf(f0.y), f2bf(f0.z), f2bf(f0.w),
                       f2bf(f1.x), f2bf(f1.y), f2bf(f1.z), f2bf(f1.w) };
        *(uint4*)&xb[(size_t)i * 8] = *(uint4*)tmp;
        return;
    }
    if (bidg >= 3576) {
        // xs-pool: one pooled row per block, 3 coalesced column passes
        const int p = bidg - 3576;                 // [0,256)
#pragma unroll
        for (int k = 0; k < 3; ++k) {
            const int c = k * 256 + tid;
            const float* src = x + (size_t)p * 32 * DIMC + c;
            float s = 0.f;
#pragma unroll
            for (int j = 0; j < 32; ++j) s += src[(size_t)j * DIMC];
            xs[(size_t)p * DIMC + c] = f2bf(s);
        }
        return;
    }
    __shared__ u16 tile[64 * 72];
    int bid = bidg - 3072;
    const float* src; u16* dst; int n0, k0, ld, col0;
    if (bid < 360) {
        int nt = bid / 12, kt = bid % 12;
        n0 = nt * 64; k0 = kt * 64; dst = Wtcat;
        if (n0 < 768)       { src = Wa; ld = 768; col0 = n0; }
        else if (n0 < 1152) { src = Wb; ld = 384; col0 = n0 - 768; }
        else                { src = Wv; ld = 768; col0 = n0 - 1152; }
    } else {
        int b2 = bid - 360;
        int nt = b2 / 12, kt = b2 % 12;
        n0 = nt * 64; k0 = kt * 64; dst = Wpt; src = Wp; ld = 768; col0 = n0;
    }
#pragma unroll
    for (int p = 0; p < 16; ++p) {
        int i = p * 256 + tid;
        int k = i >> 6, n = i & 63;
        tile[n * 72 + k] = f2bf(src[(size_t)(k0 + k) * ld + col0 + n]);
    }
    __syncthreads();
    int n = tid >> 2, kc = (tid & 3) * 16;
    uint4 o0 = *(uint4*)&tile[n * 72 + kc];
    uint4 o1 = *(uint4*)&tile[n * 72 + kc + 8];
    *(uint4*)&dst[(size_t)(n0 + n) * DIMC + k0 + kc] = o0;
    *(uint4*)&dst[(size_t)(n0 + n) * DIMC + k0 + kc + 8] = o1;
}

// ---------------------------------------------------------------------------
// bf16 MFMA GEMM — R5-verbatim. C[M,N] = A[M,K] @ Bt[N,K]^T (+bias).
// 128x128 tile, BK=32, double-buffered global_load_lds, raw s_barrier +
// s_waitcnt vmcnt(4) pipeline. grid (M/128, N/128), ldC = output stride.
// ---------------------------------------------------------------------------
template<bool WRITE_BF16>
__global__ __launch_bounds__(256)
void gemm_bf16_kernel(const u16* __restrict__ A, const u16* __restrict__ Bt,
                      const float* __restrict__ bias, void* __restrict__ Cout,
                      int K, int ldC)
{
    __shared__ u16 As[2][4096];
    __shared__ u16 Bs[2][4096];

    const int tid  = threadIdx.x;
    const int lane = tid & 63, wave = tid >> 6;
    const int quad = lane >> 4, l16 = lane & 15;
    const int wm = (wave & 1) * 64, wn = (wave >> 1) * 64;
    const int m0 = blockIdx.x * 128, n0 = blockIdx.y * 128;

    const int lrow = lane >> 2, lchunk = lane & 3;
    const u16* gA = A  + (size_t)(m0 + wave * 32 + lrow) * K + lchunk * 8;
    const u16* gB = Bt + (size_t)(n0 + wave * 32 + lrow) * K + lchunk * 8;
    const int NT = K / 32;   // 24

#define STAGE(buf, kt_) do {                                                  \
        const int _k0 = (kt_) * 32;                                           \
        async_load16(gA + _k0,          &As[buf][wave * 1024]);               \
        async_load16(gA + _k0 + 16 * K, &As[buf][wave * 1024 + 512]);         \
        async_load16(gB + _k0,          &Bs[buf][wave * 1024]);               \
        async_load16(gB + _k0 + 16 * K, &Bs[buf][wave * 1024 + 512]);         \
    } while (0)

#define COMPUTE(buf) do {                                                     \
        short8 af[4], bf[4];                                                  \
        _Pragma("unroll")                                                     \
        for (int t = 0; t < 4; ++t) {                                         \
            af[t] = *(short8*)&As[buf][(wm + t * 16 + l16) * 32 + quad * 8];  \
            bf[t] = *(short8*)&Bs[buf][(wn + t * 16 + l16) * 32 + quad * 8];  \
        }                                                                     \
        _Pragma("unroll")                                                     \
        for (int mt = 0; mt < 4; ++mt)                                        \
            _Pragma("unroll")                                                 \
            for (int nt = 0; nt < 4; ++nt)                                    \
                acc[mt][nt] = __builtin_amdgcn_mfma_f32_16x16x32_bf16(        \
                    af[mt], bf[nt], acc[mt][nt], 0, 0, 0);                    \
    } while (0)

    floatx4 acc[4][4] = {};
    STAGE(0, 0);
    STAGE(1, 1);
#pragma unroll 2
    for (int kt = 0; kt < NT; ++kt) {
        const int buf = kt & 1;
        __asm__ volatile("s_waitcnt vmcnt(4)" ::: "memory");  // retire older 4
        __asm__ volatile("s_barrier" ::: "memory");
        COMPUTE(buf);
        __asm__ volatile("s_barrier" ::: "memory");
        STAGE(buf, (kt + 2) % NT);
    }
#undef STAGE
#undef COMPUTE

#pragma unroll
    for (int mt = 0; mt < 4; ++mt)
#pragma unroll
        for (int nt = 0; nt < 4; ++nt) {
            const int gc = n0 + wn + nt * 16 + l16;
            const float bv = bias ? bias[gc] : 0.f;
#pragma unroll
            for (int r = 0; r < 4; ++r) {
                const int gr = m0 + wm + mt * 16 + quad * 4 + r;
                const float v = acc[mt][nt][r] + bv;
                if (WRITE_BF16) ((u16*)Cout)[(size_t)gr * ldC + gc] = f2bf(v);
                else            ((float*)Cout)[(size_t)gr * ldC + gc] = v;
            }
        }
}

// ---------------------------------------------------------------------------
// Standalone Vs kernel: Vs[bh][t][d] = xs[b*64+t] @ Wv[:, h*64+d]  (fp32).
// One block per bh; wave owns t-strip of 16; direct global fragment loads
// (same operand arrangement as the validated GEMM). No LDS, no barriers.
// Wvt = rows [1152,1920) of Wtcat (validated transpose).
// ---------------------------------------------------------------------------
__global__ __launch_bounds__(256)
void vs_kernel(const u16* __restrict__ xs, const u16* __restrict__ Wvt,
               float* __restrict__ Vs)
{
    const int tid = threadIdx.x;
    const int lane = tid & 63, wave = tid >> 6;
    const int quad = lane >> 4, l16 = lane & 15;
    const int bh = blockIdx.x;
    const int b = bh / HEADS, h = bh % HEADS;
    const int K = DIMC;

    const u16* gA = xs  + (size_t)(b * 64 + wave * 16 + l16) * K + quad * 8;
    const u16* gB = Wvt + (size_t)(h * 64 + l16) * K + quad * 8;

    floatx4 acc[4] = {};
    for (int it = 0; it < 24; ++it) {
        short8 af = *(const short8*)(gA + it * 32);
        short8 bf[4];
#pragma unroll
        for (int nt = 0; nt < 4; ++nt)
            bf[nt] = *(const short8*)(gB + (size_t)nt * 16 * K + it * 32);
#pragma unroll
        for (int nt = 0; nt < 4; ++nt)
            acc[nt] = __builtin_amdgcn_mfma_f32_16x16x32_bf16(
                af, bf[nt], acc[nt], 0, 0, 0);
    }
#pragma unroll
    for (int nt = 0; nt < 4; ++nt)
#pragma unroll
        for (int r = 0; r < 4; ++r) {
            const int t = wave * 16 + quad * 4 + r;
            const int d = nt * 16 + l16;
            Vs[(size_t)bh * 4096 + t * 64 + d] = acc[nt][r];
        }
}

// ---------------------------------------------------------------------------
// Attention via MFMA — R5-verbatim except Yab stride NAB.
// Block = (bh, 64-row strip); wave owns 16 rows.
// ---------------------------------------------------------------------------
__global__ __launch_bounds__(256)
void attn_kernel(const u16* __restrict__ Yab, const float* __restrict__ Vs,
                 u16* __restrict__ Hb)
{
    __shared__ u16 vsT[64 * 64];        // [d][k]
    __shared__ u16 wlds[4][16 * 64];    // per-wave P [r][k]
    const int bh = blockIdx.x;
    const int h = bh % HEADS, b = bh / HEADS;
    const int tid = threadIdx.x;

    for (int i = tid; i < 4096; i += 256) {
        int t = i >> 6, d = i & 63;
        vsT[d * 64 + t] = f2bf(Vs[(size_t)bh * 4096 + i]);
    }
    __syncthreads();

    const int lane = tid & 63, wave = tid >> 6;
    const int quad = lane >> 4, l16 = lane & 15;

    short8 bfrag[4][2];
#pragma unroll
    for (int nt = 0; nt < 4; ++nt)
#pragma unroll
        for (int kk = 0; kk < 2; ++kk)
            bfrag[nt][kk] = *(short8*)&vsT[(nt * 16 + l16) * 64 + kk * 32 + quad * 8];

    const int i0 = blockIdx.y * 64 + wave * 16;

    for (int r = 0; r < 16; ++r) {
        const size_t row = (size_t)(b * SEQ + i0 + r);
        float aval = bf2f(Yab[row * NAB + h * 64 + lane]);
        float bval = bf2f(Yab[row * NAB + 768 + h * 32 + (lane >> 1)]);
        float s = aval * bval;
        float m = s;
#pragma unroll
        for (int off = 32; off; off >>= 1) m = fmaxf(m, __shfl_xor(m, off, 64));
        float e = __expf(s - m);
        float sum = e;
#pragma unroll
        for (int off = 32; off; off >>= 1) sum += __shfl_xor(sum, off, 64);
        wlds[wave][r * 64 + lane] = f2bf(e / (32.0f * sum));
    }

    short8 af0 = *(short8*)&wlds[wave][l16 * 64 + quad * 8];
    short8 af1 = *(short8*)&wlds[wave][l16 * 64 + 32 + quad * 8];

    floatx4 acc[4] = {};
#pragma unroll
    for (int nt = 0; nt < 4; ++nt) {
        acc[nt] = __builtin_amdgcn_mfma_f32_16x16x32_bf16(af0, bfrag[nt][0], acc[nt], 0, 0, 0);
        acc[nt] = __builtin_amdgcn_mfma_f32_16x16x32_bf16(af1, bfrag[nt][1], acc[nt], 0, 0, 0);
    }

#pragma unroll
    for (int nt = 0; nt < 4; ++nt)
#pragma unroll
        for (int rr = 0; rr < 4; ++rr) {
            const size_t row = (size_t)(b * SEQ + i0 + quad * 4 + rr);
            Hb[row * DIMC + h * 64 + nt * 16 + l16] = f2bf(acc[nt][rr]);
        }
}

// ---------------------------------------------------------------------------
extern "C" void kernel_launch(void* const* d_in, const int* in_sizes, int n_in,
                              void* d_out, int out_size, void* d_ws, size_t ws_size,
                              hipStream_t stream)
{
    const float* x  = (const float*)d_in[0];
    const float* Wa = (const float*)d_in[1];
    const float* Wb = (const float*)d_in[2];
    const float* Wv = (const float*)d_in[3];
    const float* Wp = (const float*)d_in[4];
    const float* bp = (const float*)d_in[5];
    float* out = (float*)d_out;

    char* ws = (char*)d_ws;
    u16*   xb    = (u16*)ws;   ws += (size_t)MROWS * DIMC * 2;   // 12.6 MB
    u16*   Wtcat = (u16*)ws;   ws += (size_t)NCAT * DIMC * 2;    // 2.9 MB
    u16*   Wpt   = (u16*)ws;   ws += (size_t)DIMC * DIMC * 2;    // 1.2 MB
    u16*   xs    = (u16*)ws;   ws += (size_t)256 * DIMC * 2;     // 0.4 MB
    u16*   Yab   = (u16*)ws;   ws += (size_t)MROWS * NAB * 2;    // 18.9 MB
    float* Vs    = (float*)ws; ws += (size_t)48 * 4096 * 4;      // 0.8 MB
    u16*   Hb    = (u16*)ws;                                     // 12.6 MB

    dim3 blk(256);

    prep_kernel<<<dim3(3832), blk, 0, stream>>>(x, Wa, Wb, Wv, Wp,
                                                xb, Wtcat, Wpt, xs);

    vs_kernel<<<dim3(48), blk, 0, stream>>>(xs, Wtcat + (size_t)NAB * DIMC, Vs);

    gemm_bf16_kernel<true><<<dim3(MROWS / 128, NAB / 128), blk, 0, stream>>>(
        xb, Wtcat, nullptr, Yab, DIMC, NAB);

    attn_kernel<<<dim3(BATCH * HEADS, SEQ / 64), blk, 0, stream>>>(Yab, Vs, Hb);

    gemm_bf16_kernel<false><<<dim3(MROWS / 128, DIMC / 128), blk, 0, stream>>>(
        Hb, Wpt, bp, out, DIMC, DIMC);
}